// Round 6
// baseline (463.057 us; speedup 1.0000x reference)
//
#include <hip/hip_runtime.h>
#include <hip/hip_bf16.h>

// GNNClassifier: 3x SAGEConv(mean) + ReLU -> global_mean_pool -> Linear+ReLU -> Linear
// N=50000 nodes, E=800000 edges, IN=128, HID=256, OUT=10, G=64 graphs.
//
// R6: GEMM double-buffered LDS (1 barrier/iter, loads overlap MFMA), paired
// epilogue stores; CSR scan fused to one kernel; count/fill vectorized x4;
// cursor zeroing folded into cvt. agg left as-is (measured at service ceiling:
// R4/R5 both 55us, ~7.4 TB/s effective on random 512B gathers).

#define HID 256
typedef unsigned short ushort_t;
typedef __bf16 bf16x8 __attribute__((ext_vector_type(8)));
typedef float  f32x4  __attribute__((ext_vector_type(4)));

__device__ __forceinline__ unsigned short f2bf(float f) {
    unsigned int u = __float_as_uint(f);
    unsigned int r = (u + 0x7fffu + ((u >> 16) & 1u)) >> 16;
    return (unsigned short)r;
}
__device__ __forceinline__ float bflo(unsigned int u) { return __uint_as_float(u << 16); }
__device__ __forceinline__ float bfhi(unsigned int u) { return __uint_as_float(u & 0xffff0000u); }
__device__ __forceinline__ unsigned int packbf(float a, float b) {
    return (unsigned int)f2bf(a) | ((unsigned int)f2bf(b) << 16);
}
__device__ __forceinline__ void gld16(const void* g, void* l) {
    __builtin_amdgcn_global_load_lds(
        (const __attribute__((address_space(1))) unsigned int*)g,
        (__attribute__((address_space(3))) unsigned int*)l, 16, 0, 0);
}
__device__ __forceinline__ void fma8(float* a, float w, const uint4 v) {
    a[0] = fmaf(w, bflo(v.x), a[0]); a[1] = fmaf(w, bfhi(v.x), a[1]);
    a[2] = fmaf(w, bflo(v.y), a[2]); a[3] = fmaf(w, bfhi(v.y), a[3]);
    a[4] = fmaf(w, bflo(v.z), a[4]); a[5] = fmaf(w, bfhi(v.z), a[5]);
    a[6] = fmaf(w, bflo(v.w), a[6]); a[7] = fmaf(w, bfhi(v.w), a[7]);
}
__device__ __forceinline__ void acc8(float* a, const uint4 v) {
    a[0] += bflo(v.x); a[1] += bfhi(v.x);
    a[2] += bflo(v.y); a[3] += bfhi(v.y);
    a[4] += bflo(v.z); a[5] += bfhi(v.z);
    a[6] += bflo(v.w); a[7] += bfhi(v.w);
}
__device__ __forceinline__ int4 load4idx(const int* __restrict__ csr, int pbase, int e1m1) {
    int4 r;
    r.x = csr[min(pbase + 0, e1m1)];
    r.y = csr[min(pbase + 1, e1m1)];
    r.z = csr[min(pbase + 2, e1m1)];
    r.w = csr[min(pbase + 3, e1m1)];
    return r;
}

// ------------------------------------------- fused conversion (+ cursor zero)
__global__ __launch_bounds__(256)
void cvt_kernel(const float* __restrict__ x, ushort_t* __restrict__ xb, int nx4,
                const float* __restrict__ W1l, const float* __restrict__ W1r,
                const float* __restrict__ W2l, const float* __restrict__ W2r,
                const float* __restrict__ W3l, const float* __restrict__ W3r,
                ushort_t* __restrict__ wdst, int s1, int s2,
                int* __restrict__ cursor, int nn) {
    const int t = blockIdx.x * 256 + threadIdx.x;
    if (t < (nn + 3) / 4) *(int4*)(cursor + t * 4) = make_int4(0, 0, 0, 0);
    if (t < nx4) {
        const int i = t * 4;
        const float4 v = *(const float4*)(x + i);
        *(uint2*)(xb + i) = make_uint2(packbf(v.x, v.y), packbf(v.z, v.w));
        return;
    }
    int off = t - nx4;
    const int total = 2 * s1 + 4 * s2;
    if (off >= total) return;
    const int i = off;
    const float* src;
    if (off < s1) src = W1l;
    else if ((off -= s1) < s1) src = W1r;
    else if ((off -= s1) < s2) src = W2l;
    else if ((off -= s2) < s2) src = W2r;
    else if ((off -= s2) < s2) src = W3l;
    else { off -= s2; src = W3r; }
    wdst[i] = f2bf(src[off]);
}

// ---------------------------------------------------------------- CSR build
__global__ __launch_bounds__(256)
void count_deg_kernel(const int* __restrict__ dst, int* __restrict__ hist, int E) {
    int i = (blockIdx.x * 256 + threadIdx.x) * 4;
    if (i + 3 < E) {
        const int4 d = *(const int4*)(dst + i);
        atomicAdd(&hist[d.x], 1); atomicAdd(&hist[d.y], 1);
        atomicAdd(&hist[d.z], 1); atomicAdd(&hist[d.w], 1);
    } else {
        for (; i < E; ++i) atomicAdd(&hist[dst[i]], 1);
    }
}

// single fused scan: block b redundantly reduces hist[0..b*1024) for its base,
// then locally scans its 1024 elems; writes offsets + cursor.
__global__ __launch_bounds__(256)
void scan_kernel(const int* __restrict__ hist, int* __restrict__ offsets,
                 int* __restrict__ cursor, int nn, int E) {
    const int tid = threadIdx.x, lane = tid & 63, wid = tid >> 6;
    const int b0 = blockIdx.x * 1024;
    // --- block base: sum of hist[0..b0) (b0 is a multiple of 1024)
    int part = 0;
    for (int i = tid * 4; i + 3 < b0; i += 1024) {
        const int4 v = *(const int4*)(hist + i);
        part += v.x + v.y + v.z + v.w;
    }
    #pragma unroll
    for (int d = 1; d < 64; d <<= 1) part += __shfl_xor(part, d, 64);
    __shared__ int wsum[4];
    if (lane == 0) wsum[wid] = part;
    __syncthreads();
    const int base = wsum[0] + wsum[1] + wsum[2] + wsum[3];
    __syncthreads();
    // --- local scan of hist[b0 .. b0+1024)
    const int i0 = b0 + tid * 4;
    int v0 = (i0 + 0 < nn) ? hist[i0 + 0] : 0;
    int v1 = (i0 + 1 < nn) ? hist[i0 + 1] : 0;
    int v2 = (i0 + 2 < nn) ? hist[i0 + 2] : 0;
    int v3 = (i0 + 3 < nn) ? hist[i0 + 3] : 0;
    const int s = v0 + v1 + v2 + v3;
    int incl = s;
    #pragma unroll
    for (int d = 1; d < 64; d <<= 1) {
        int t = __shfl_up(incl, d, 64);
        if (lane >= d) incl += t;
    }
    __shared__ int wt[4];
    if (lane == 63) wt[wid] = incl;
    __syncthreads();
    int wbase = 0;
    #pragma unroll
    for (int w = 0; w < 4; ++w) { int t = wt[w]; if (w < wid) wbase += t; }
    int e = base + wbase + (incl - s);
    if (i0 + 0 < nn) { offsets[i0 + 0] = e; cursor[i0 + 0] = e; }  e += v0;
    if (i0 + 1 < nn) { offsets[i0 + 1] = e; cursor[i0 + 1] = e; }  e += v1;
    if (i0 + 2 < nn) { offsets[i0 + 2] = e; cursor[i0 + 2] = e; }  e += v2;
    if (i0 + 3 < nn) { offsets[i0 + 3] = e; cursor[i0 + 3] = e; }
    if (blockIdx.x == gridDim.x - 1 && tid == 0) offsets[nn] = E;
}

__global__ __launch_bounds__(256)
void fill_csr_kernel(const int* __restrict__ src, const int* __restrict__ dst,
                     int* __restrict__ cursor, int* __restrict__ csr, int E) {
    int i = (blockIdx.x * 256 + threadIdx.x) * 4;
    if (i + 3 < E) {
        const int4 d = *(const int4*)(dst + i);
        const int4 sv = *(const int4*)(src + i);
        csr[atomicAdd(&cursor[d.x], 1)] = sv.x;
        csr[atomicAdd(&cursor[d.y], 1)] = sv.y;
        csr[atomicAdd(&cursor[d.z], 1)] = sv.z;
        csr[atomicAdd(&cursor[d.w], 1)] = sv.w;
    } else {
        for (; i < E; ++i) csr[atomicAdd(&cursor[dst[i]], 1)] = src[i];
    }
}

// ---------------------------------------------------------------- aggregation (bf16)
template <int C>
__global__ __launch_bounds__(256)
void agg_kernel(const ushort_t* __restrict__ h, const int* __restrict__ offsets,
                const int* __restrict__ csr, ushort_t* __restrict__ out, int nn) {
    constexpr int CL = C / 8;
    constexpr int EW = 64 / CL;
    constexpr int RPE = 4 * EW;
    const int node = (blockIdx.x * 256 + threadIdx.x) >> 6;
    if (node >= nn) return;
    const int lane = threadIdx.x & 63;
    const int cl = lane & (CL - 1);
    const int eo = lane / CL;
    const int e0 = offsets[node], e1 = offsets[node + 1];
    const int deg = e1 - e0;
    const int rounds = (deg + RPE - 1) / RPE;
    const int e1m1 = max(e1 - 1, 0);
    float a[8] = {0.f, 0.f, 0.f, 0.f, 0.f, 0.f, 0.f, 0.f};
    int pb = e0 + eo * 4;
    if (rounds > 0) {
        int4 idx = load4idx(csr, pb, e1m1);
        for (int r2 = 0; r2 < rounds; ++r2) {
            const int4 cur = idx;
            const int pcur = pb;
            pb += RPE;
            if (r2 + 1 < rounds) idx = load4idx(csr, pb, e1m1);
            const uint4 v0 = *(const uint4*)(h + (size_t)cur.x * C + cl * 8);
            const uint4 v1 = *(const uint4*)(h + (size_t)cur.y * C + cl * 8);
            const uint4 v2 = *(const uint4*)(h + (size_t)cur.z * C + cl * 8);
            const uint4 v3 = *(const uint4*)(h + (size_t)cur.w * C + cl * 8);
            fma8(a, (pcur + 0 < e1) ? 1.f : 0.f, v0);
            fma8(a, (pcur + 1 < e1) ? 1.f : 0.f, v1);
            fma8(a, (pcur + 2 < e1) ? 1.f : 0.f, v2);
            fma8(a, (pcur + 3 < e1) ? 1.f : 0.f, v3);
        }
    }
    #pragma unroll
    for (int d = CL; d < 64; d <<= 1)
        #pragma unroll
        for (int r = 0; r < 8; ++r) a[r] += __shfl_xor(a[r], d, 64);
    if (eo == 0) {
        const float inv = 1.0f / fmaxf((float)deg, 1.0f);
        uint4 o;
        o.x = packbf(a[0] * inv, a[1] * inv);
        o.y = packbf(a[2] * inv, a[3] * inv);
        o.z = packbf(a[4] * inv, a[5] * inv);
        o.w = packbf(a[6] * inv, a[7] * inv);
        *(uint4*)(out + (size_t)node * C + cl * 8) = o;
    }
}

// ---------------------------------------------------------------- MFMA dual GEMM
// C[M,256] = relu(A1@W1^T + A2@W2^T + bias); 128x128 tile, 4 waves of 64x64.
// Double-buffered LDS (64KB): one barrier per k-iter; stage(t+1) issues right
// after the barrier and overlaps MFMA on tile t.
template <int K>
__global__ __launch_bounds__(256, 2)
void gemm2_mfma(const ushort_t* __restrict__ A1, const ushort_t* __restrict__ A2,
                const ushort_t* __restrict__ W1, const ushort_t* __restrict__ W2,
                const float* __restrict__ bias, ushort_t* __restrict__ Cout, int M) {
    __shared__ ushort_t As[2][128 * 64];
    __shared__ ushort_t Bs[2][128 * 64];
    const int tid = threadIdx.x;
    const int row0 = blockIdx.x * 128, col0 = blockIdx.y * 128;
    const int wave = tid >> 6, lane = tid & 63;
    const int wm = (wave & 1) * 64, wn = (wave >> 1) * 64;
    const int l15 = lane & 15, quad = lane >> 4;
    constexpr int TPK = K / 64;
    constexpr int T = 2 * TPK;

    f32x4 acc[4][4] = {};

    auto stage = [&](int t, int buf) {
        const int phase = t / TPK;
        const int kt = (t % TPK) * 64;
        const ushort_t* __restrict__ A = phase ? A2 : A1;
        const ushort_t* __restrict__ W = phase ? W2 : W1;
        #pragma unroll
        for (int p = 0; p < 4; ++p) {
            const int slot = p * 256 + tid;
            const int r = slot >> 3, c = slot & 7;
            const int cg = c ^ (r & 7);
            int ar = row0 + r; if (ar >= M) ar = M - 1;
            gld16(A + (size_t)ar * K + kt + cg * 8, &As[buf][slot * 8]);
        }
        #pragma unroll
        for (int p = 0; p < 4; ++p) {
            const int slot = p * 256 + tid;
            const int r = slot >> 3, c = slot & 7;
            const int cg = c ^ (r & 7);
            gld16(W + (size_t)(col0 + r) * K + kt + cg * 8, &Bs[buf][slot * 8]);
        }
    };

    stage(0, 0);
    #pragma unroll
    for (int t = 0; t < T; ++t) {
        const int cur = t & 1;
        __syncthreads();                     // stage(t) visible; buf[1-cur] free
        if (t + 1 < T) stage(t + 1, 1 - cur);  // overlaps compute below
        #pragma unroll
        for (int ks = 0; ks < 2; ++ks) {
            bf16x8 af[4], bfv[4];
            #pragma unroll
            for (int i = 0; i < 4; ++i) {
                const int r = wm + i * 16 + l15;
                const int cl = (ks * 4 + quad) ^ (r & 7);
                af[i] = *(const bf16x8*)&As[cur][r * 64 + cl * 8];
            }
            #pragma unroll
            for (int j = 0; j < 4; ++j) {
                const int r = wn + j * 16 + l15;
                const int cl = (ks * 4 + quad) ^ (r & 7);
                bfv[j] = *(const bf16x8*)&Bs[cur][r * 64 + cl * 8];
            }
            #pragma unroll
            for (int i = 0; i < 4; ++i)
                #pragma unroll
                for (int j = 0; j < 4; ++j)
                    acc[i][j] = __builtin_amdgcn_mfma_f32_16x16x32_bf16(
                        af[i], bfv[j], acc[i][j], 0, 0, 0);
        }
    }

    // epilogue: lane pair (l15, l15^1) packs two adjacent n into one dword store
    #pragma unroll
    for (int i = 0; i < 4; ++i) {
        const int mbase = row0 + wm + i * 16 + quad * 4;
        #pragma unroll
        for (int j = 0; j < 4; ++j) {
            const int n = col0 + wn + j * 16 + l15;
            const float b = bias[n];
            #pragma unroll
            for (int reg = 0; reg < 4; ++reg) {
                const int mr = mbase + reg;
                const float v = fmaxf(acc[i][j][reg] + b, 0.f);
                const float vp = __shfl_xor(v, 1, 64);
                if (!(l15 & 1) && mr < M)
                    *(unsigned int*)(Cout + (size_t)mr * 256 + n) = packbf(v, vp);
            }
        }
    }
}

// ---------------------------------------------------------------- fused pool+MLP
__global__ __launch_bounds__(256)
void pool_mlp_kernel(const ushort_t* __restrict__ h, const int* __restrict__ batch, int nn,
                     const float* __restrict__ lin1W, const float* __restrict__ lin1b,
                     const float* __restrict__ lin2W, const float* __restrict__ lin2b,
                     float* __restrict__ out) {
    const int g = blockIdx.x;
    const int tid = threadIdx.x;
    int lo = 0, hi = nn;
    while (lo < hi) { int mid = (lo + hi) >> 1; if (batch[mid] < g) lo = mid + 1; else hi = mid; }
    const int s = lo;
    hi = nn;
    while (lo < hi) { int mid = (lo + hi) >> 1; if (batch[mid] < g + 1) lo = mid + 1; else hi = mid; }
    const int e = lo;

    const int cl = tid & 31, rg = tid >> 5;
    float a[8] = {0.f, 0.f, 0.f, 0.f, 0.f, 0.f, 0.f, 0.f};
    for (int n = s + rg; n < e; n += 8) {
        const uint4 v = *(const uint4*)(h + (size_t)n * 256 + cl * 8);
        acc8(a, v);
    }
    __shared__ float red[8][256];
    #pragma unroll
    for (int r = 0; r < 8; ++r) red[rg][cl * 8 + r] = a[r];
    __syncthreads();
    __shared__ float meanv[256];
    float ssum = 0.f;
    #pragma unroll
    for (int r = 0; r < 8; ++r) ssum += red[r][tid];
    meanv[tid] = ssum / fmaxf((float)(e - s), 1.0f);
    __syncthreads();
    __shared__ float g1[128];
    if (tid < 128) {
        float acc = lin1b[tid];
        #pragma unroll 4
        for (int k = 0; k < 256; k += 4) {
            const float4 w = *(const float4*)(lin1W + tid * 256 + k);
            acc += meanv[k] * w.x + meanv[k + 1] * w.y + meanv[k + 2] * w.z + meanv[k + 3] * w.w;
        }
        g1[tid] = fmaxf(acc, 0.f);
    }
    __syncthreads();
    if (tid < 10) {
        float o = lin2b[tid];
        #pragma unroll 4
        for (int k = 0; k < 128; k += 4) {
            const float4 w = *(const float4*)(lin2W + tid * 128 + k);
            o += g1[k] * w.x + g1[k + 1] * w.y + g1[k + 2] * w.z + g1[k + 3] * w.w;
        }
        out[g * 10 + tid] = o;
    }
}

// ---------------------------------------------------------------- launcher
extern "C" void kernel_launch(void* const* d_in, const int* in_sizes, int n_in,
                              void* d_out, int out_size, void* d_ws, size_t ws_size,
                              hipStream_t stream) {
    const float* x     = (const float*)d_in[0];
    const int*   eidx  = (const int*)d_in[1];
    const int*   batch = (const int*)d_in[2];
    const float* W1l = (const float*)d_in[3];
    const float* b1  = (const float*)d_in[4];
    const float* W1r = (const float*)d_in[5];
    const float* W2l = (const float*)d_in[6];
    const float* b2  = (const float*)d_in[7];
    const float* W2r = (const float*)d_in[8];
    const float* W3l = (const float*)d_in[9];
    const float* b3  = (const float*)d_in[10];
    const float* W3r = (const float*)d_in[11];
    const float* lin1W = (const float*)d_in[12];
    const float* lin1b = (const float*)d_in[13];
    const float* lin2W = (const float*)d_in[14];
    const float* lin2b = (const float*)d_in[15];
    float* out = (float*)d_out;

    const int E  = in_sizes[1] / 2;
    const int NN = in_sizes[2];
    const int IN = 128;
    const int* src = eidx;
    const int* dst = eidx + E;

    char* ws = (char*)d_ws;
    size_t off = 0;
    auto alloc = [&](size_t bytes) { void* p = ws + off; off += (bytes + 255) / 256 * 256; return p; };
    ushort_t* xb  = (ushort_t*)alloc((size_t)NN * IN * 2);
    ushort_t* agg = (ushort_t*)alloc((size_t)NN * HID * 2);
    ushort_t* hA  = (ushort_t*)alloc((size_t)NN * HID * 2);
    ushort_t* hB  = (ushort_t*)alloc((size_t)NN * HID * 2);
    const int s1 = HID * IN, s2 = HID * HID;
    ushort_t* wb  = (ushort_t*)alloc((size_t)(2 * s1 + 4 * s2) * 2);
    int* offsets   = (int*)alloc((size_t)(NN + 1) * 4);
    int* cursor    = (int*)alloc((size_t)(NN + 4) * 4);
    int* csr       = (int*)alloc((size_t)E * 4);
    (void)ws_size; (void)n_in; (void)out_size;

    const ushort_t* W1lb = wb;
    const ushort_t* W1rb = wb + s1;
    const ushort_t* W2lb = wb + 2 * s1;
    const ushort_t* W2rb = wb + 2 * s1 + s2;
    const ushort_t* W3lb = wb + 2 * s1 + 2 * s2;
    const ushort_t* W3rb = wb + 2 * s1 + 3 * s2;

    const int TB = 256;
    const int mgrid = (NN + 127) / 128;
    const int sgrid = (NN + 1023) / 1024;

    // --- fused conversion + cursor zero ---
    const int nx4 = NN * IN / 4;
    const int wtotal = 2 * s1 + 4 * s2;
    cvt_kernel<<<(nx4 + wtotal + TB - 1) / TB, TB, 0, stream>>>(
        x, xb, nx4, W1l, W1r, W2l, W2r, W3l, W3r, wb, s1, s2, cursor, NN);

    // --- CSR build ---
    count_deg_kernel<<<(E / 4 + TB - 1) / TB, TB, 0, stream>>>(dst, cursor, E);
    scan_kernel<<<sgrid, TB, 0, stream>>>(cursor, offsets, cursor, NN, E);
    fill_csr_kernel<<<(E / 4 + TB - 1) / TB, TB, 0, stream>>>(src, dst, cursor, csr, E);

    // --- layer 1 (K=128) ---
    agg_kernel<128><<<(NN + 3) / 4, TB, 0, stream>>>(xb, offsets, csr, agg, NN);
    gemm2_mfma<128><<<dim3(mgrid, 2), TB, 0, stream>>>(agg, xb, W1lb, W1rb, b1, hA, NN);
    // --- layer 2 ---
    agg_kernel<256><<<(NN + 3) / 4, TB, 0, stream>>>(hA, offsets, csr, agg, NN);
    gemm2_mfma<256><<<dim3(mgrid, 2), TB, 0, stream>>>(agg, hA, W2lb, W2rb, b2, hB, NN);
    // --- layer 3 ---
    agg_kernel<256><<<(NN + 3) / 4, TB, 0, stream>>>(hB, offsets, csr, agg, NN);
    gemm2_mfma<256><<<dim3(mgrid, 2), TB, 0, stream>>>(agg, hB, W3lb, W3rb, b3, hA, NN);

    // --- fused pool + MLP ---
    pool_mlp_kernel<<<64, TB, 0, stream>>>(hA, batch, NN, lin1W, lin1b, lin2W, lin2b, out);
}